// Round 1
// baseline (57.431 us; speedup 1.0000x reference)
//
#include <hip/hip_runtime.h>

// Problem constants (from reference):
//   x: (16, 3, 512, 512) fp32; K=8, S=4, P=0
//   Ho = Wo = (512-8)/4 + 1 = 127
//   out: (16, 127*127, 3, 64) fp32
// out[b, ho*Wo+wo, c, kh*K+kw] = x[b, c, ho*S+kh, wo*S+kw]
//
// Innermost 64 outputs (kk dim) for a fixed (b,p,c) split into 16 float4s;
// float4 #j covers kh=j>>1, kw0=(j&1)*4 -> 4 CONTIGUOUS input floats at a
// 16B-aligned address. So this is a permuted float4 copy:
//   out4[i] = in4 at (((b*C+c)*H + ho*S+kh)*W + wo*S + kw0) / 4

namespace {
constexpr int B  = 16;
constexpr int C  = 3;
constexpr int H  = 512;
constexpr int W  = 512;
constexpr int K  = 8;
constexpr int S  = 4;
constexpr int Ho = 127;
constexpr int Wo = 127;
constexpr int P  = Ho * Wo;            // 16129 patches per (b)
constexpr int N4 = B * P * C * (K * K / 4);  // total float4s = 12,387,072
}

__global__ __launch_bounds__(256) void
PatchesKernel3D_34892314313629_kernel(const float* __restrict__ x,
                                      float* __restrict__ out) {
    const int stride = gridDim.x * blockDim.x;
    for (int i = blockIdx.x * blockDim.x + threadIdx.x; i < N4; i += stride) {
        // i = ((b*P + p)*C + c)*16 + j
        const int j  = i & 15;
        const int t  = i >> 4;          // (b*P + p)*C + c
        const int c  = t % C;           // magic-mul (const divisor)
        const int t2 = t / C;           // b*P + p
        const int p  = t2 % P;          // magic-mul
        const int b  = t2 / P;
        const int ho = p / Wo;          // magic-mul
        const int wo = p - ho * Wo;

        const int kh  = j >> 1;
        const int kw0 = (j & 1) << 2;

        const size_t src_off =
            ((size_t)((b * C + c) * H + ho * S + kh)) * W + (wo * S + kw0);

        const float4 v = *reinterpret_cast<const float4*>(x + src_off);
        reinterpret_cast<float4*>(out)[i] = v;
    }
}

extern "C" void kernel_launch(void* const* d_in, const int* in_sizes, int n_in,
                              void* d_out, int out_size, void* d_ws, size_t ws_size,
                              hipStream_t stream) {
    const float* x = (const float*)d_in[0];
    float* out = (float*)d_out;

    const int block = 256;
    // memory-bound: cap grid and grid-stride (≈8 blocks/CU on 256 CUs)
    int grid = (N4 + block - 1) / block;
    if (grid > 2048) grid = 2048;

    PatchesKernel3D_34892314313629_kernel<<<grid, block, 0, stream>>>(x, out);
}

// Round 2
// 42.094 us; speedup vs baseline: 1.3644x; 1.3644x over previous
//
#include <hip/hip_runtime.h>

// im2col permuted copy, fp32:
//   x: (16, 3, 512, 512); K=8, S=4, P=0; Ho=Wo=127
//   out[b, ho*127+wo, c, kh*8+kw] = x[b, c, ho*4+kh, wo*4+kw]
//
// Strategy: one workgroup per (b, ho).
//   Input  for (b,ho): 3 channels x 8 contiguous rows = 3 x 16KB CONTIGUOUS
//          blocks -> coalesced float4 loads -> LDS (row stride padded to 516
//          floats so the read phase is bank-conflict-free).
//   Output for (b,ho): out[b, ho*127 .. ho*127+126, :, :] is one CONTIGUOUS
//          95.25 KB region -> coalesced float4 stores.
//   The awkward permutation happens in LDS (69 TB/s), both HBM streams are
//   pure streaming.

namespace {
constexpr int B  = 16;
constexpr int C  = 3;
constexpr int H  = 512;
constexpr int W  = 512;
constexpr int S  = 4;
constexpr int Ho = 127;
constexpr int Wo = 127;
constexpr int P  = Ho * Wo;           // patches per batch
constexpr int ROW_PAD = W + 4;        // 516 floats: 4*kh mod 32 spreads banks
constexpr int LDS_FLOATS = C * 8 * ROW_PAD;     // 12384 floats = 48.4 KB
constexpr int IN_F4_PER_C = 8 * W / 4;          // 1024 float4 per channel block
constexpr int OUT_F4_PER_GROUP = Wo * C * 16;   // 6096 float4 per (b,ho)
constexpr int NWG = B * Ho;                     // 2032 = 8 * 254
}

__global__ __launch_bounds__(256) void
PatchesKernel3D_34892314313629_kernel(const float* __restrict__ x,
                                      float* __restrict__ out) {
    __shared__ float lds[LDS_FLOATS];

    // XCD-bijective swizzle: 2032 % 8 == 0, chunk = 254 per XCD.
    // Consecutive logical ids within an XCD share 4 of 8 input rows -> L2 hits.
    const int bid = (int)blockIdx.x;
    const int logical = (bid & 7) * (NWG / 8) + (bid >> 3);
    const int b  = logical / Ho;
    const int ho = logical - b * Ho;

    const int tid = (int)threadIdx.x;

    // ---- Phase 1: global -> LDS, coalesced ----
    // Per channel c: rows ho*4 .. ho*4+7 are one contiguous 16 KB block.
    const float4* __restrict__ x4 = reinterpret_cast<const float4*>(x);
    #pragma unroll
    for (int l = tid; l < C * IN_F4_PER_C; l += 256) {
        const int c = l >> 10;               // IN_F4_PER_C = 1024
        const int r = l & 1023;              // float4 index within block
        const size_t src4 =
            ((size_t)((b * C + c) * H + ho * S) * W) / 4 + r;
        const float4 v = x4[src4];
        const int row  = r >> 7;             // 128 float4 per row
        const int col4 = r & 127;
        *reinterpret_cast<float4*>(&lds[c * 8 * ROW_PAD + row * ROW_PAD + col4 * 4]) = v;
    }

    __syncthreads();

    // ---- Phase 2: LDS -> global, coalesced ----
    // out float4 region for (b,ho): base + [0, 6096), contiguous.
    float4* __restrict__ out4 = reinterpret_cast<float4*>(out);
    const size_t out_base4 = ((size_t)(b * P + ho * Wo) * C) * 16;

    for (int o = tid; o < OUT_F4_PER_GROUP; o += 256) {
        const int j  = o & 15;               // which float4 of the 64-elem kk dim
        const int q  = o >> 4;               // wo*3 + c
        const int c  = q % 3;
        const int wo = q / 3;
        const int kh  = j >> 1;
        const int kw0 = (j & 1) << 2;
        const float4 v = *reinterpret_cast<const float4*>(
            &lds[c * 8 * ROW_PAD + kh * ROW_PAD + wo * S + kw0]);
        out4[out_base4 + o] = v;
    }
}

extern "C" void kernel_launch(void* const* d_in, const int* in_sizes, int n_in,
                              void* d_out, int out_size, void* d_ws, size_t ws_size,
                              hipStream_t stream) {
    const float* x = (const float*)d_in[0];
    float* out = (float*)d_out;
    PatchesKernel3D_34892314313629_kernel<<<NWG, 256, 0, stream>>>(x, out);
}